// Round 1
// 84.068 us; speedup vs baseline: 1.0432x; 1.0432x over previous
//
#include <hip/hip_runtime.h>
#include <stdint.h>

// OpenBoundary neighbour list, N=8192, cutoff 0.125, max_neighbours=128.
// R5: cell-centric neigh kernel. 4 dispatches:
//   memset  : zero cnt[512] + partial[256] (3 KB)
//   scatter : point i -> cells[cell][atomicAdd(cnt[cell])] (order-free;
//             bitmap enumeration restores index order later)
//   neigh   : 1 block (512 thr, 8 waves) per CELL. Stage the 27-cell
//             candidate set (T~432 pts, bound 27*CAP) into LDS once,
//             amortised over the ~16 rows of the cell. Each wave owns
//             rows r = wave, wave+8, ... and tests them against the LDS
//             candidate list at full 64-lane utilisation (~7 b128 reads
//             per row). Hits -> per-wave 1KB LDS bitmap (atomicOr);
//             lane-major bit enumeration + shfl scan emits ascending
//             indices (jnp.argwhere order). Also zeroes the row's
//             cell_indices[128][3] slice and atomicMax's the uncapped
//             count into partial[block & 255].
//   maxred  : max over 256 partials -> scalar output.

#define CUTOFF2 (0.125f * 0.125f)
constexpr int NCELLS = 512;   // 8^3
constexpr int CAP    = 64;    // slots/cell; occupancy ~Poisson(16), max~32
constexpr int MAXN   = 128;
constexpr int NPART  = 256;
constexpr int CANDMAX = 27 * CAP;   // hard bound on staged candidates (27 KB)

__device__ __forceinline__ int ccoord(float v) {
    int c = (int)(v * 8.0f);
    return c > 7 ? 7 : c;
}

__global__ __launch_bounds__(256) void scatter_kernel(
    const float* __restrict__ pos, int n,
    int* __restrict__ cnt, float4* __restrict__ cells) {
    int i = blockIdx.x * blockDim.x + threadIdx.x;
    if (i >= n) return;
    float x = pos[i*3], y = pos[i*3+1], z = pos[i*3+2];
    int c = (ccoord(z) * 8 + ccoord(y)) * 8 + ccoord(x);
    int slot = atomicAdd(&cnt[c], 1);
    cells[c * CAP + slot] = make_float4(x, y, z, __int_as_float(i));
}

__global__ __launch_bounds__(512) void neigh_kernel(
    const float4* __restrict__ cells,
    const int* __restrict__ cnt,
    int maxn,
    int* __restrict__ to_idx,
    int* __restrict__ cell_out,     // [n, maxn, 3] zeros
    int* __restrict__ partial) {
    __shared__ float4   cand[CANDMAX];   // staged stencil candidates
    __shared__ uint32_t bm[8][256];      // per-wave 8192-bit bitmap
    __shared__ int scid[27], scnt[27], soff[28];

    const int tid  = threadIdx.x;
    const int lane = tid & 63;
    const int wave = tid >> 6;
    const int cell = blockIdx.x;
    const int cx = cell & 7, cy = (cell >> 3) & 7, cz = cell >> 6;

    // --- stencil setup: wave 0, lanes 0..26 load cnts, shfl-scan prefix ---
    if (tid < 64) {
        int dzz = tid / 9 - 1, dyy = (tid / 3) % 3 - 1, dxx = tid % 3 - 1;
        int xx = cx + dxx, yy = cy + dyy, zz = cz + dzz;
        bool ok = (tid < 27) & ((unsigned)xx <= 7u) &
                  ((unsigned)yy <= 7u) & ((unsigned)zz <= 7u);
        int c = (zz * 8 + yy) * 8 + xx;
        int v = ok ? cnt[c] : 0;
        if (tid < 27) { scid[tid] = ok ? c : -1; scnt[tid] = v; }
        int incl = v;
        #pragma unroll
        for (int d = 1; d < 32; d <<= 1) {
            int o = __shfl_up(incl, d);
            if (lane >= d) incl += o;
        }
        if (tid < 27) soff[tid + 1] = incl;
        if (tid == 0) soff[0] = 0;
    }
    __syncthreads();

    const int mrows = scnt[13];          // center cell (dz=dy=dx=0) -> idx 13
    const int cbase = soff[13];
    if (mrows == 0) return;              // uniform per block: no barrier after

    // --- stage candidates into LDS: wave j handles stencil cells j, j+8, ... ---
    for (int j = wave; j < 27; j += 8) {
        int c = scid[j];
        if (c >= 0 && lane < scnt[j])
            cand[soff[j] + lane] = cells[c * CAP + lane];
    }
    __syncthreads();

    const int T = soff[27];
    uint32_t* mybm = bm[wave];

    // --- row loop: each wave owns rows wave, wave+8, ... of this cell ---
    for (int r = wave; r < mrows; r += 8) {
        float4 me = cand[cbase + r];          // broadcast read
        const int row = __float_as_int(me.w);

        ((int4*)mybm)[lane] = make_int4(0, 0, 0, 0);   // zero bitmap

        // zero this row's cell_indices slice (96 int4), overlaps with tests
        int4* co = (int4*)(cell_out + (size_t)row * maxn * 3);
        co[lane] = make_int4(0, 0, 0, 0);
        if (lane < 32) co[64 + lane] = make_int4(0, 0, 0, 0);

        // full-lane test loop over LDS candidates, 2x unrolled for ILP
        int s = lane;
        for (; s + 64 < T; s += 128) {
            float4 q0 = cand[s];
            float4 q1 = cand[s + 64];
            float dx0 = q0.x - me.x, dy0 = q0.y - me.y, dz0 = q0.z - me.z;
            float dx1 = q1.x - me.x, dy1 = q1.y - me.y, dz1 = q1.z - me.z;
            float d20 = dx0*dx0 + dy0*dy0 + dz0*dz0;
            float d21 = dx1*dx1 + dy1*dy1 + dz1*dz1;
            int i0 = __float_as_int(q0.w);
            int i1 = __float_as_int(q1.w);
            if (d20 <= CUTOFF2 && i0 != row)
                atomicOr(&mybm[i0 >> 5], 1u << (i0 & 31));
            if (d21 <= CUTOFF2 && i1 != row)
                atomicOr(&mybm[i1 >> 5], 1u << (i1 & 31));
        }
        if (s < T) {
            float4 q = cand[s];
            float ddx = q.x - me.x, ddy = q.y - me.y, ddz = q.z - me.z;
            float d2 = ddx*ddx + ddy*ddy + ddz*ddz;
            int i0 = __float_as_int(q.w);
            if (d2 <= CUTOFF2 && i0 != row)
                atomicOr(&mybm[i0 >> 5], 1u << (i0 & 31));
        }

        // lane-major 128-bit slice -> ascending global index order
        int4 wv = ((int4*)mybm)[lane];
        uint32_t w0 = (uint32_t)wv.x, w1 = (uint32_t)wv.y,
                 w2 = (uint32_t)wv.z, w3 = (uint32_t)wv.w;
        int tc = __popc(w0) + __popc(w1) + __popc(w2) + __popc(w3);

        int inc = tc;
        #pragma unroll
        for (int d = 1; d < 64; d <<= 1) {
            int o = __shfl_up(inc, d);
            if (lane >= d) inc += o;
        }
        const int total = __shfl(inc, 63);   // uncapped neighbour count
        int p = inc - tc;                    // exclusive prefix

        int* out_row = to_idx + (size_t)row * maxn;
        const int bitbase = lane << 7;
        uint32_t wsv[4] = {w0, w1, w2, w3};
        #pragma unroll
        for (int d = 0; d < 4; ++d) {
            uint32_t mm = wsv[d];
            while (mm) {
                int b = __ffs(mm) - 1;
                if (p < MAXN) out_row[p] = bitbase + (d << 5) + b;
                ++p;
                mm &= mm - 1;
            }
        }
        int start = total < MAXN ? total : MAXN;
        for (int q = start + lane; q < MAXN; q += 64) out_row[q] = -1;

        if (lane == 0) atomicMax(&partial[blockIdx.x & (NPART - 1)], total);
    }
}

__global__ __launch_bounds__(256) void maxred_kernel(
    const int* __restrict__ partial, int* __restrict__ out_max) {
    __shared__ int sm[4];
    int m = partial[threadIdx.x];
    #pragma unroll
    for (int d = 32; d > 0; d >>= 1) {
        int o = __shfl_down(m, d);
        m = o > m ? o : m;
    }
    if ((threadIdx.x & 63) == 0) sm[threadIdx.x >> 6] = m;
    __syncthreads();
    if (threadIdx.x == 0) {
        int r = sm[0];
        r = sm[1] > r ? sm[1] : r;
        r = sm[2] > r ? sm[2] : r;
        *out_max = r > sm[3] ? r : sm[3];
    }
}

extern "C" void kernel_launch(void* const* d_in, const int* in_sizes, int n_in,
                              void* d_out, int out_size, void* d_ws, size_t ws_size,
                              hipStream_t stream) {
    const float* pos = (const float*)d_in[0];
    const int n = in_sizes[0] / 3;                       // 8192
    const int maxn = (out_size - 1) / (n * 4);           // 128

    int* to_idx   = (int*)d_out;
    int* cell_out = to_idx + (size_t)n * maxn;           // [n, maxn, 3]
    int* out_max  = cell_out + (size_t)n * maxn * 3;     // scalar

    // ws: cnt[512] | partial[256] | pad | cells float4[512*64]
    int*    cnt     = (int*)d_ws;
    int*    partial = cnt + NCELLS;
    float4* cells   = (float4*)((char*)d_ws + 4096);

    hipMemsetAsync(d_ws, 0, (NCELLS + NPART) * sizeof(int), stream);
    scatter_kernel<<<(n + 255) / 256, 256, 0, stream>>>(pos, n, cnt, cells);
    neigh_kernel<<<NCELLS, 512, 0, stream>>>(cells, cnt, maxn,
                                             to_idx, cell_out, partial);
    maxred_kernel<<<1, NPART, 0, stream>>>(partial, out_max);
}